// Round 1
// baseline (389.041 us; speedup 1.0000x reference)
//
#include <hip/hip_runtime.h>
#include <hip/hip_bf16.h>
#include <stdint.h>

// Problem: B=8192, E=1024, P=512. x:[8192,2048] f32, w:[1024,512] f32, b:[512] f32.
// out: scalar f32 = mean_i( -S[i, i^4096]/T + log(sum_{j!=i} exp(S[i,j]/T)) ),
// S = zn @ zn^T, zn = rownorm(relu(x_pairrows) @ w + b), T=0.1.
//
// ws layout (bytes):
//   wt  bf16 [512][1024]    @ 0          (w transposed, 1 MB)
//   xb  bf16 [16384][1024]  @ 1048576    (relu(x) cast, 32 MB)
//   z   f32  [16384][512]   @ 34603008   (projection, 32 MB)
//   zn  bf16 [8192][1024]   @ 68157440   (normalized rows, 16 MB)
//   sumexp f32[8192]        @ 84934656
//   pos    f32[8192]        @ 84967424
// total ~85 MB.

typedef __attribute__((ext_vector_type(8))) __bf16 bf16x8;
typedef __attribute__((ext_vector_type(4))) float f32x4;

__device__ __forceinline__ unsigned short f2bf(float f) {
  union { float f; unsigned int u; } v; v.f = f;
  unsigned int u = v.u;
  u += 0x7FFFu + ((u >> 16) & 1u);   // round-to-nearest-even
  return (unsigned short)(u >> 16);
}

// ---------------- prep: xb = bf16(relu(x)); wt = bf16(w^T); sumexp = 0 -------
__global__ __launch_bounds__(256) void prep_kernel(
    const float* __restrict__ x, const float* __restrict__ w,
    unsigned short* __restrict__ xb, unsigned short* __restrict__ wt,
    float* __restrict__ sumexp) {
  int tid = blockIdx.x * 256 + threadIdx.x;            // 16384 blocks -> 4,194,304
  float4 v = ((const float4*)x)[tid];                  // 16,777,216 elems / 4
  ushort4 o;
  o.x = f2bf(fmaxf(v.x, 0.f));
  o.y = f2bf(fmaxf(v.y, 0.f));
  o.z = f2bf(fmaxf(v.z, 0.f));
  o.w = f2bf(fmaxf(v.w, 0.f));
  ((ushort4*)xb)[tid] = o;
  if (tid < 512 * 1024) {                              // w^T: coalesced writes
    int k = tid & 1023, n = tid >> 10;
    wt[(n << 10) + k] = f2bf(w[k * 512 + n]);
  }
  if (tid < 8192) sumexp[tid] = 0.f;
}

// ---------------- shared GEMM machinery (128x128 tile, BK=32, 4 waves) -------
// LDS chunk c (16B) holds rows/kg per: row = (c>>6)*16 + (c&15), kg = (c>>4)&3.
// -> fragment ds_read_b128: 8 consecutive lanes hit 8 distinct bank-quads.
__device__ __forceinline__ void stage_tile(const unsigned short* __restrict__ g,
                                           int ldg, unsigned short* s, int tid) {
#pragma unroll
  for (int t = 0; t < 2; ++t) {
    int c = t * 256 + tid;
    int row = ((c >> 6) << 4) | (c & 15);
    int kg = (c >> 4) & 3;
    __builtin_amdgcn_global_load_lds(
        (const __attribute__((address_space(1))) void*)(g + row * ldg + kg * 8),
        (__attribute__((address_space(3))) void*)(s + (c & ~63) * 8),
        16, 0, 0);
  }
}

__device__ __forceinline__ bf16x8 frag_ld(const unsigned short* s, int wq, int t, int L) {
  int c = ((wq + t) << 6) | (((L >> 4) << 4) | (L & 15));
  return *(const bf16x8*)(s + c * 8);
}

// ---------------- GEMM1: z[16384,512] = xb @ wt^T + b ------------------------
__global__ __launch_bounds__(256) void gemm1_kernel(
    const unsigned short* __restrict__ xb, const unsigned short* __restrict__ wt,
    const float* __restrict__ bias, float* __restrict__ z) {
  __shared__ unsigned short As[4096] __attribute__((aligned(16)));
  __shared__ unsigned short Bs[4096] __attribute__((aligned(16)));
  int tid = threadIdx.x, L = tid & 63, w = tid >> 6;
  int wm = w >> 1, wn = w & 1;
  int i0 = blockIdx.x * 128, n0 = blockIdx.y * 128;
  f32x4 acc[4][4];
#pragma unroll
  for (int a = 0; a < 4; ++a)
#pragma unroll
    for (int bq = 0; bq < 4; ++bq) acc[a][bq] = (f32x4)0.f;
  const unsigned short* Ag = xb + i0 * 1024;
  const unsigned short* Bg = wt + n0 * 1024;
  for (int k0 = 0; k0 < 1024; k0 += 32) {
    __syncthreads();
    stage_tile(Ag + k0, 1024, As, tid);
    stage_tile(Bg + k0, 1024, Bs, tid);
    __syncthreads();
    bf16x8 af[4], bf[4];
#pragma unroll
    for (int t = 0; t < 4; ++t) af[t] = frag_ld(As, wm * 4, t, L);
#pragma unroll
    for (int t = 0; t < 4; ++t) bf[t] = frag_ld(Bs, wn * 4, t, L);
#pragma unroll
    for (int mt = 0; mt < 4; ++mt)
#pragma unroll
      for (int nt = 0; nt < 4; ++nt)
        acc[mt][nt] = __builtin_amdgcn_mfma_f32_16x16x32_bf16(
            af[mt], bf[nt], acc[mt][nt], 0, 0, 0);
  }
  int rbase = i0 + wm * 64 + ((L >> 4) << 2);
  int cbase = n0 + wn * 64 + (L & 15);
#pragma unroll
  for (int nt = 0; nt < 4; ++nt) {
    int n = cbase + nt * 16;
    float bn = bias[n];
#pragma unroll
    for (int mt = 0; mt < 4; ++mt)
#pragma unroll
      for (int r = 0; r < 4; ++r) {
        int i = rbase + mt * 16 + r;
        z[i * 512 + n] = acc[mt][nt][r] + bn;
      }
  }
}

// ---------------- normalize: zn[8192,1024] = bf16(z_row / max(||z_row||,eps)) -
__global__ __launch_bounds__(256) void norm_kernel(const float* __restrict__ z,
                                                   unsigned short* __restrict__ zn) {
  int row = blockIdx.x, t = threadIdx.x;
  float4 v = ((const float4*)z)[row * 256 + t];
  float ss = v.x * v.x + v.y * v.y + v.z * v.z + v.w * v.w;
#pragma unroll
  for (int off = 1; off < 64; off <<= 1) ss += __shfl_xor(ss, off);
  __shared__ float red[4];
  if ((t & 63) == 0) red[t >> 6] = ss;
  __syncthreads();
  float tot = red[0] + red[1] + red[2] + red[3];
  float inv = 1.f / fmaxf(sqrtf(tot), 1e-8f);
  ushort4 o;
  o.x = f2bf(v.x * inv); o.y = f2bf(v.y * inv);
  o.z = f2bf(v.z * inv); o.w = f2bf(v.w * inv);
  ((ushort4*)zn)[row * 256 + t] = o;
}

// ---------------- GEMM2 fused: sumexp[i] += sum_j exp(10*zn_i.zn_j), pos ------
__global__ __launch_bounds__(256) void gemm2_kernel(
    const unsigned short* __restrict__ zn,
    float* __restrict__ sumexp, float* __restrict__ pos) {
  __shared__ unsigned short As[4096] __attribute__((aligned(16)));
  __shared__ unsigned short Bs[4096] __attribute__((aligned(16)));
  int tid = threadIdx.x, L = tid & 63, w = tid >> 6;
  int wm = w >> 1, wn = w & 1;
  int i0 = blockIdx.x * 128, j0 = blockIdx.y * 128;
  f32x4 acc[4][4];
#pragma unroll
  for (int a = 0; a < 4; ++a)
#pragma unroll
    for (int bq = 0; bq < 4; ++bq) acc[a][bq] = (f32x4)0.f;
  const unsigned short* Ag = zn + i0 * 1024;
  const unsigned short* Bg = zn + j0 * 1024;
  for (int k0 = 0; k0 < 1024; k0 += 32) {
    __syncthreads();
    stage_tile(Ag + k0, 1024, As, tid);
    stage_tile(Bg + k0, 1024, Bs, tid);
    __syncthreads();
    bf16x8 af[4], bf[4];
#pragma unroll
    for (int t = 0; t < 4; ++t) af[t] = frag_ld(As, wm * 4, t, L);
#pragma unroll
    for (int t = 0; t < 4; ++t) bf[t] = frag_ld(Bs, wn * 4, t, L);
#pragma unroll
    for (int mt = 0; mt < 4; ++mt)
#pragma unroll
      for (int nt = 0; nt < 4; ++nt)
        acc[mt][nt] = __builtin_amdgcn_mfma_f32_16x16x32_bf16(
            af[mt], bf[nt], acc[mt][nt], 0, 0, 0);
  }
  // epilogue: scale 1/T=10, mask diag, extract pos, exp, per-row reduce
  float rs[4][4];
#pragma unroll
  for (int mt = 0; mt < 4; ++mt)
#pragma unroll
    for (int r = 0; r < 4; ++r) rs[mt][r] = 0.f;
  int ib = i0 + wm * 64 + ((L >> 4) << 2);
  int jb = j0 + wn * 64 + (L & 15);
#pragma unroll
  for (int mt = 0; mt < 4; ++mt)
#pragma unroll
    for (int nt = 0; nt < 4; ++nt) {
      int j = jb + nt * 16;
#pragma unroll
      for (int r = 0; r < 4; ++r) {
        int i = ib + mt * 16 + r;
        float s = acc[mt][nt][r] * 10.f;
        if (j == (i ^ 4096)) pos[i] = s;
        float e = (i == j) ? 0.f : __expf(s);
        rs[mt][r] += e;
      }
    }
  // reduce across the 16 lanes sharing a row (lane bits 0-3)
#pragma unroll
  for (int mt = 0; mt < 4; ++mt)
#pragma unroll
    for (int r = 0; r < 4; ++r) {
      float v = rs[mt][r];
      v += __shfl_xor(v, 1); v += __shfl_xor(v, 2);
      v += __shfl_xor(v, 4); v += __shfl_xor(v, 8);
      rs[mt][r] = v;
    }
  // lane (L&15) reports (mt,r) = (sel>>2, sel&3) for its quad's 4-row group
  int sel = L & 15;
  float myv = rs[0][0];
#pragma unroll
  for (int mt = 0; mt < 4; ++mt)
#pragma unroll
    for (int r = 0; r < 4; ++r)
      if (sel == mt * 4 + r) myv = rs[mt][r];
  int row = i0 + wm * 64 + (sel >> 2) * 16 + ((L >> 4) << 2) + (sel & 3);
  atomicAdd(&sumexp[row], myv);
}

// ---------------- finalize: out = mean(log(sumexp) - pos) --------------------
__global__ __launch_bounds__(1024) void finalize_kernel(
    const float* __restrict__ sumexp, const float* __restrict__ pos,
    float* __restrict__ out) {
  int t = threadIdx.x;
  float s = 0.f;
  for (int i = t; i < 8192; i += 1024) s += logf(sumexp[i]) - pos[i];
#pragma unroll
  for (int off = 1; off < 64; off <<= 1) s += __shfl_xor(s, off);
  __shared__ float red[16];
  if ((t & 63) == 0) red[t >> 6] = s;
  __syncthreads();
  if (t == 0) {
    float tot = 0.f;
    for (int k2 = 0; k2 < 16; ++k2) tot += red[k2];
    out[0] = tot * (1.0f / 8192.0f);
  }
}

extern "C" void kernel_launch(void* const* d_in, const int* in_sizes, int n_in,
                              void* d_out, int out_size, void* d_ws, size_t ws_size,
                              hipStream_t stream) {
  const float* x = (const float*)d_in[0];
  const float* w = (const float*)d_in[1];
  const float* b = (const float*)d_in[2];
  float* out = (float*)d_out;
  char* ws = (char*)d_ws;
  unsigned short* wt = (unsigned short*)(ws);
  unsigned short* xb = (unsigned short*)(ws + 1048576);
  float* z           = (float*)(ws + 34603008);
  unsigned short* zn = (unsigned short*)(ws + 68157440);
  float* sumexp      = (float*)(ws + 84934656);
  float* pos         = (float*)(ws + 84967424);

  prep_kernel<<<16384, 256, 0, stream>>>(x, w, xb, wt, sumexp);
  gemm1_kernel<<<dim3(128, 4), 256, 0, stream>>>(xb, wt, b, z);
  norm_kernel<<<8192, 256, 0, stream>>>(z, zn);
  gemm2_kernel<<<dim3(64, 64), 256, 0, stream>>>(zn, sumexp, pos);
  finalize_kernel<<<1, 1024, 0, stream>>>(sumexp, pos, out);
}

// Round 2
// 308.520 us; speedup vs baseline: 1.2610x; 1.2610x over previous
//
#include <hip/hip_runtime.h>
#include <hip/hip_bf16.h>
#include <stdint.h>

// Problem: B=8192, E=1024, P=512. x:[8192,2048] f32, w:[1024,512] f32, b:[512] f32.
// out: scalar f32 = mean_i( -S[i, i^4096]/T + log(sum_{j!=i} exp(S[i,j]/T)) ),
// S = zn @ zn^T (SYMMETRIC -> compute upper triangle only), T=0.1.
//
// ws layout (bytes):
//   wt  bf16 [512][1024]    @ 0
//   xb  bf16 [16384][1024]  @ 1048576
//   z   f32  [16384][512]   @ 34603008
//   zn  bf16 [8192][1024]   @ 68157440
//   sumexp f32[8192]        @ 84934656
//   pos    f32[8192]        @ 84967424

typedef __attribute__((ext_vector_type(8))) __bf16 bf16x8;
typedef __attribute__((ext_vector_type(4))) float f32x4;

__device__ __forceinline__ unsigned short f2bf(float f) {
  union { float f; unsigned int u; } v; v.f = f;
  unsigned int u = v.u;
  u += 0x7FFFu + ((u >> 16) & 1u);   // round-to-nearest-even
  return (unsigned short)(u >> 16);
}

// ---------------- prep: xb = bf16(relu(x)); wt = bf16(w^T); sumexp = 0 -------
__global__ __launch_bounds__(256) void prep_kernel(
    const float* __restrict__ x, const float* __restrict__ w,
    unsigned short* __restrict__ xb, unsigned short* __restrict__ wt,
    float* __restrict__ sumexp) {
  int tid = blockIdx.x * 256 + threadIdx.x;
  float4 v = ((const float4*)x)[tid];
  ushort4 o;
  o.x = f2bf(fmaxf(v.x, 0.f));
  o.y = f2bf(fmaxf(v.y, 0.f));
  o.z = f2bf(fmaxf(v.z, 0.f));
  o.w = f2bf(fmaxf(v.w, 0.f));
  ((ushort4*)xb)[tid] = o;
  if (tid < 512 * 1024) {
    int k = tid & 1023, n = tid >> 10;
    wt[(n << 10) + k] = f2bf(w[k * 512 + n]);
  }
  if (tid < 8192) sumexp[tid] = 0.f;
}

// ------------- BK=64 staging: 128 rows x 64 k (16 KB) as 2 sub-tiles ---------
// Within each 8KB sub-tile: chunk cc (16B): row = (cc>>6)*16 + (cc&15),
// kgroup = (cc>>4)&3. LDS dest per instr = wave-uniform base + lane*16.
__device__ __forceinline__ void stage_tile64(const unsigned short* __restrict__ g,
                                             int ldg, unsigned short* s, int tid) {
#pragma unroll
  for (int t = 0; t < 4; ++t) {
    int c = t * 256 + tid;          // [0,1024)
    int sub = c >> 9;               // wave-uniform per t
    int cc = c & 511;
    int row = ((cc >> 6) << 4) | (cc & 15);
    int kg = (cc >> 4) & 3;
    __builtin_amdgcn_global_load_lds(
        (const __attribute__((address_space(1))) void*)(g + row * ldg + sub * 32 + kg * 8),
        (__attribute__((address_space(3))) void*)(s + sub * 4096 + (cc & ~63) * 8),
        16, 0, 0);
  }
}

__device__ __forceinline__ bf16x8 frag_ld(const unsigned short* s, int wq, int t, int L) {
  int c = ((wq + t) << 6) | L;
  return *(const bf16x8*)(s + c * 8);
}

// ---------------- GEMM1: z[16384,512] = xb @ wt^T + b ------------------------
__global__ __launch_bounds__(256) void gemm1_kernel(
    const unsigned short* __restrict__ xb, const unsigned short* __restrict__ wt,
    const float* __restrict__ bias, float* __restrict__ z) {
  __shared__ unsigned short As[8192] __attribute__((aligned(16)));
  __shared__ unsigned short Bs[8192] __attribute__((aligned(16)));
  int tid = threadIdx.x, L = tid & 63, w = tid >> 6;
  int wm = w >> 1, wn = w & 1;
  int i0 = blockIdx.x * 128, n0 = blockIdx.y * 128;
  f32x4 acc[4][4];
#pragma unroll
  for (int a = 0; a < 4; ++a)
#pragma unroll
    for (int bq = 0; bq < 4; ++bq) acc[a][bq] = (f32x4)0.f;
  const unsigned short* Ag = xb + i0 * 1024;
  const unsigned short* Bg = wt + n0 * 1024;
  for (int k0 = 0; k0 < 1024; k0 += 64) {
    __syncthreads();
    stage_tile64(Ag + k0, 1024, As, tid);
    stage_tile64(Bg + k0, 1024, Bs, tid);
    __syncthreads();
#pragma unroll
    for (int sub = 0; sub < 2; ++sub) {
      bf16x8 af[4], bf[4];
#pragma unroll
      for (int t = 0; t < 4; ++t) af[t] = frag_ld(As + sub * 4096, wm * 4, t, L);
#pragma unroll
      for (int t = 0; t < 4; ++t) bf[t] = frag_ld(Bs + sub * 4096, wn * 4, t, L);
#pragma unroll
      for (int mt = 0; mt < 4; ++mt)
#pragma unroll
        for (int nt = 0; nt < 4; ++nt)
          acc[mt][nt] = __builtin_amdgcn_mfma_f32_16x16x32_bf16(
              af[mt], bf[nt], acc[mt][nt], 0, 0, 0);
    }
  }
  int rbase = i0 + wm * 64 + ((L >> 4) << 2);
  int cbase = n0 + wn * 64 + (L & 15);
#pragma unroll
  for (int nt = 0; nt < 4; ++nt) {
    int n = cbase + nt * 16;
    float bn = bias[n];
#pragma unroll
    for (int mt = 0; mt < 4; ++mt)
#pragma unroll
      for (int r = 0; r < 4; ++r) {
        int i = rbase + mt * 16 + r;
        z[i * 512 + n] = acc[mt][nt][r] + bn;
      }
  }
}

// ---------------- normalize: zn = bf16(z_row / max(||z_row||,eps)) ------------
__global__ __launch_bounds__(256) void norm_kernel(const float* __restrict__ z,
                                                   unsigned short* __restrict__ zn) {
  int row = blockIdx.x, t = threadIdx.x;
  float4 v = ((const float4*)z)[row * 256 + t];
  float ss = v.x * v.x + v.y * v.y + v.z * v.z + v.w * v.w;
#pragma unroll
  for (int off = 1; off < 64; off <<= 1) ss += __shfl_xor(ss, off);
  __shared__ float red[4];
  if ((t & 63) == 0) red[t >> 6] = ss;
  __syncthreads();
  float tot = red[0] + red[1] + red[2] + red[3];
  float inv = 1.f / fmaxf(sqrtf(tot), 1e-8f);
  ushort4 o;
  o.x = f2bf(v.x * inv); o.y = f2bf(v.y * inv);
  o.z = f2bf(v.z * inv); o.w = f2bf(v.w * inv);
  ((ushort4*)zn)[row * 256 + t] = o;
}

// -------- GEMM2 symmetric: upper-triangle blocks only (2080 of 4096) ---------
// Off-diagonal blocks contribute row-sums to sumexp[i] AND col-sums to
// sumexp[j]; pos pair (i, i^4096) written from its unique block.
__global__ __launch_bounds__(256) void gemm2_kernel(
    const unsigned short* __restrict__ zn,
    float* __restrict__ sumexp, float* __restrict__ pos) {
  __shared__ unsigned short As[8192] __attribute__((aligned(16)));
  __shared__ unsigned short Bs[8192] __attribute__((aligned(16)));
  // triangular decode: blockIdx.x in [0,2080) -> (bi, bj), bi <= bj
  int rem = blockIdx.x, bi = 0;
  while (rem >= 64 - bi) { rem -= 64 - bi; ++bi; }
  int bj = bi + rem;
  bool diag = (bi == bj);
  int i0 = bi * 128, j0 = bj * 128;

  int tid = threadIdx.x, L = tid & 63, w = tid >> 6;
  int wm = w >> 1, wn = w & 1;
  f32x4 acc[4][4];
#pragma unroll
  for (int a = 0; a < 4; ++a)
#pragma unroll
    for (int bq = 0; bq < 4; ++bq) acc[a][bq] = (f32x4)0.f;
  const unsigned short* Ag = zn + i0 * 1024;
  const unsigned short* Bg = zn + j0 * 1024;
  for (int k0 = 0; k0 < 1024; k0 += 64) {
    __syncthreads();
    stage_tile64(Ag + k0, 1024, As, tid);
    stage_tile64(Bg + k0, 1024, Bs, tid);
    __syncthreads();
#pragma unroll
    for (int sub = 0; sub < 2; ++sub) {
      bf16x8 af[4], bf[4];
#pragma unroll
      for (int t = 0; t < 4; ++t) af[t] = frag_ld(As + sub * 4096, wm * 4, t, L);
#pragma unroll
      for (int t = 0; t < 4; ++t) bf[t] = frag_ld(Bs + sub * 4096, wn * 4, t, L);
#pragma unroll
      for (int mt = 0; mt < 4; ++mt)
#pragma unroll
        for (int nt = 0; nt < 4; ++nt)
          acc[mt][nt] = __builtin_amdgcn_mfma_f32_16x16x32_bf16(
              af[mt], bf[nt], acc[mt][nt], 0, 0, 0);
    }
  }
  // epilogue: scale 1/T=10, mask diag, pos, exp, row+col reductions
  float rs[4][4];
  float cs[4] = {0.f, 0.f, 0.f, 0.f};
#pragma unroll
  for (int mt = 0; mt < 4; ++mt)
#pragma unroll
    for (int r = 0; r < 4; ++r) rs[mt][r] = 0.f;
  int ib = i0 + wm * 64 + ((L >> 4) << 2);
  int jb = j0 + wn * 64 + (L & 15);
#pragma unroll
  for (int mt = 0; mt < 4; ++mt)
#pragma unroll
    for (int nt = 0; nt < 4; ++nt) {
      int j = jb + nt * 16;
#pragma unroll
      for (int r = 0; r < 4; ++r) {
        int i = ib + mt * 16 + r;
        float s = acc[mt][nt][r] * 10.f;
        if (j == (i ^ 4096)) { pos[i] = s; pos[j] = s; }
        float e = (i == j) ? 0.f : __expf(s);
        rs[mt][r] += e;
        if (!diag) cs[nt] += e;
      }
    }
  // row reduction across 16 lanes sharing a row (lane bits 0-3)
#pragma unroll
  for (int mt = 0; mt < 4; ++mt)
#pragma unroll
    for (int r = 0; r < 4; ++r) {
      float v = rs[mt][r];
      v += __shfl_xor(v, 1); v += __shfl_xor(v, 2);
      v += __shfl_xor(v, 4); v += __shfl_xor(v, 8);
      rs[mt][r] = v;
    }
  int sel = L & 15;
  float myv = rs[0][0];
#pragma unroll
  for (int mt = 0; mt < 4; ++mt)
#pragma unroll
    for (int r = 0; r < 4; ++r)
      if (sel == mt * 4 + r) myv = rs[mt][r];
  int row = i0 + wm * 64 + (sel >> 2) * 16 + ((L >> 4) << 2) + (sel & 3);
  atomicAdd(&sumexp[row], myv);
  // column reduction across lanes sharing a column (lane bits 4-5)
  if (!diag) {
#pragma unroll
    for (int nt = 0; nt < 4; ++nt) {
      float v = cs[nt];
      v += __shfl_xor(v, 16); v += __shfl_xor(v, 32);
      if ((L >> 4) == 0) atomicAdd(&sumexp[jb + nt * 16], v);
    }
  }
}

// ---------------- finalize: out = mean(log(sumexp) - pos) --------------------
__global__ __launch_bounds__(1024) void finalize_kernel(
    const float* __restrict__ sumexp, const float* __restrict__ pos,
    float* __restrict__ out) {
  int t = threadIdx.x;
  float s = 0.f;
  for (int i = t; i < 8192; i += 1024) s += logf(sumexp[i]) - pos[i];
#pragma unroll
  for (int off = 1; off < 64; off <<= 1) s += __shfl_xor(s, off);
  __shared__ float red[16];
  if ((t & 63) == 0) red[t >> 6] = s;
  __syncthreads();
  if (t == 0) {
    float tot = 0.f;
    for (int k2 = 0; k2 < 16; ++k2) tot += red[k2];
    out[0] = tot * (1.0f / 8192.0f);
  }
}

extern "C" void kernel_launch(void* const* d_in, const int* in_sizes, int n_in,
                              void* d_out, int out_size, void* d_ws, size_t ws_size,
                              hipStream_t stream) {
  const float* x = (const float*)d_in[0];
  const float* w = (const float*)d_in[1];
  const float* b = (const float*)d_in[2];
  float* out = (float*)d_out;
  char* ws = (char*)d_ws;
  unsigned short* wt = (unsigned short*)(ws);
  unsigned short* xb = (unsigned short*)(ws + 1048576);
  float* z           = (float*)(ws + 34603008);
  unsigned short* zn = (unsigned short*)(ws + 68157440);
  float* sumexp      = (float*)(ws + 84934656);
  float* pos         = (float*)(ws + 84967424);

  prep_kernel<<<16384, 256, 0, stream>>>(x, w, xb, wt, sumexp);
  gemm1_kernel<<<dim3(128, 4), 256, 0, stream>>>(xb, wt, b, z);
  norm_kernel<<<8192, 256, 0, stream>>>(z, zn);
  gemm2_kernel<<<2080, 256, 0, stream>>>(zn, sumexp, pos);
  finalize_kernel<<<1, 1024, 0, stream>>>(sumexp, pos, out);
}